// Round 1
// baseline (532.314 us; speedup 1.0000x reference)
//
#include <hip/hip_runtime.h>

#define NT     256          // threads per block
#define TILE   64           // output tile (64x64)
#define XROWS  70           // x halo rows loaded  (TILE+6 needed rows: oy-2 .. oy+67)
#define XCOLS  72           // x LDS row stride (cols 0..69 loaded, 70/71 slack for vec reads)
#define XLOADC 70           // x cols actually loaded
#define DDW    68           // dd is [68][68] (s-values on 68x68, 66x66 used by blur)
#define PH     1024
#define PW     1024
#define NMT    289          // 17*17 s-phase micro-tiles (4x4 each -> covers 68x68)

__device__ __forceinline__ int iclamp(int v, int hi) {
    return v < 0 ? 0 : (v > hi ? hi : v);
}

extern "C" __global__ void __launch_bounds__(NT, 4)
nsml_loss_kernel(const float* __restrict__ A, const float* __restrict__ B,
                 double* __restrict__ acc) {
    __shared__ float xs[XROWS][XCOLS];   // 70*72*4 = 20160 B
    __shared__ float dd[DDW][DDW];       // 68*68*4 = 18496 B
    __shared__ float wpart[NT / 64];

    const int tid = threadIdx.x;
    const int ox  = blockIdx.x * TILE;
    const int oy  = blockIdx.y * TILE;
    const size_t base = (size_t)blockIdx.z * (size_t)(PH * PW);

    // vectorized global loads valid when the whole col window [ox-2, ox+68) is in-plane
    const bool vecok = (ox >= 2) && (ox + 68 <= PW);

    for (int pass = 0; pass < 2; ++pass) {
        const float* __restrict__ src = (pass == 0 ? A : B) + base;

        // ---- stage x tile (with edge clamp), x = 0.5*(t+1) ----
        if (vecok) {
            for (int idx = tid; idx < XROWS * 35; idx += NT) {
                int r  = idx / 35, c2 = idx - r * 35;       // 35 float2 per row = 70 cols
                int gy = iclamp(oy - 2 + r, PH - 1);
                const float2 v = *(const float2*)&src[(size_t)gy * PW + (ox - 2) + c2 * 2];
                float2 w;
                w.x = 0.5f * (v.x + 1.0f);
                w.y = 0.5f * (v.y + 1.0f);
                *(float2*)&xs[r][c2 * 2] = w;
            }
        } else {
            for (int idx = tid; idx < XROWS * XLOADC; idx += NT) {
                int r  = idx / XLOADC, c = idx - r * XLOADC;
                int gy = iclamp(oy - 2 + r, PH - 1);
                int gx = iclamp(ox - 2 + c, PW - 1);
                xs[r][c] = 0.5f * (src[(size_t)gy * PW + gx] + 1.0f);
            }
        }
        __syncthreads();

        // ---- s-phase: dd = sA^2 (pass 0) / dd -= sB^2 (pass 1) ----
        // micro-tile: 4x4 s-values; reads xs rows p0..p0+5, cols [q0, q0+8)
        for (int m = tid; m < NMT; m += NT) {
            int q0 = (m % 17) * 4;
            int p0 = (m / 17) * 4;
            float r[6][8];
            #pragma unroll
            for (int i = 0; i < 6; ++i) {
                float4 a = *(const float4*)&xs[p0 + i][q0];
                float4 b = *(const float4*)&xs[p0 + i][q0 + 4];
                r[i][0] = a.x; r[i][1] = a.y; r[i][2] = a.z; r[i][3] = a.w;
                r[i][4] = b.x; r[i][5] = b.y; r[i][6] = b.z; r[i][7] = b.w;
            }
            #pragma unroll
            for (int i = 0; i < 4; ++i) {
                float o[4];
                #pragma unroll
                for (int j = 0; j < 4; ++j) {
                    float c = r[i + 1][j + 1];
                    float ortho = fabsf(c - r[i][j + 1]) + fabsf(c - r[i + 2][j + 1])
                                + fabsf(c - r[i + 1][j]) + fabsf(c - r[i + 1][j + 2]);
                    float diag  = fabsf(c - r[i][j])     + fabsf(c - r[i + 2][j + 2])
                                + fabsf(c - r[i][j + 2]) + fabsf(c - r[i + 2][j]);
                    float s = ortho + 0.707f * diag;
                    int gy = oy - 1 + p0 + i;
                    int gx = ox - 1 + q0 + j;
                    bool in = ((unsigned)gy < (unsigned)PH) & ((unsigned)gx < (unsigned)PW);
                    o[j] = in ? s * s : 0.0f;   // zero-pad semantics for the blur
                }
                float4 w = make_float4(o[0], o[1], o[2], o[3]);
                float4* dst = (float4*)&dd[p0 + i][q0];
                if (pass == 0) {
                    *dst = w;
                } else {
                    float4 old = *dst;
                    *dst = make_float4(old.x - w.x, old.y - w.y, old.z - w.z, old.w - w.w);
                }
            }
        }
        __syncthreads();
    }

    // ---- separable 3x3 Gaussian of dd, square, accumulate ----
    // each thread: one 4x4 output micro-tile; reads dd rows ty0..ty0+5, cols [tx0, tx0+8)
    float ta = 0.0f;
    {
        int tx0 = (tid & 15) * 4;
        int ty0 = (tid >> 4) * 4;
        float r[6][8];
        #pragma unroll
        for (int i = 0; i < 6; ++i) {
            float4 a = *(const float4*)&dd[ty0 + i][tx0];
            float4 b = *(const float4*)&dd[ty0 + i][tx0 + 4];
            r[i][0] = a.x; r[i][1] = a.y; r[i][2] = a.z; r[i][3] = a.w;
            r[i][4] = b.x; r[i][5] = b.y; r[i][6] = b.z; r[i][7] = b.w;
        }
        float h[6][4];
        #pragma unroll
        for (int i = 0; i < 6; ++i)
            #pragma unroll
            for (int j = 0; j < 4; ++j)
                h[i][j] = r[i][j] + 2.0f * r[i][j + 1] + r[i][j + 2];
        #pragma unroll
        for (int i = 0; i < 4; ++i)
            #pragma unroll
            for (int j = 0; j < 4; ++j) {
                float g = 0.0625f * (h[i][j] + 2.0f * h[i + 1][j] + h[i + 2][j]);
                ta += g * g;
            }
    }

    // ---- block reduce -> double atomic ----
    #pragma unroll
    for (int off = 32; off > 0; off >>= 1) ta += __shfl_down(ta, off, 64);
    if ((tid & 63) == 0) wpart[tid >> 6] = ta;
    __syncthreads();
    if (tid == 0) {
        double t = (double)wpart[0] + (double)wpart[1] + (double)wpart[2] + (double)wpart[3];
        atomicAdd(acc, t);
    }
}

extern "C" __global__ void finalize_kernel(const double* __restrict__ acc,
                                           float* __restrict__ out, double inv_n) {
    out[0] = (float)(acc[0] * inv_n);
}

extern "C" void kernel_launch(void* const* d_in, const int* in_sizes, int n_in,
                              void* d_out, int out_size, void* d_ws, size_t ws_size,
                              hipStream_t stream) {
    const float* A = (const float*)d_in[0];
    const float* B = (const float*)d_in[1];
    float* out  = (float*)d_out;
    double* acc = (double*)d_ws;

    const long long n = (long long)in_sizes[0];
    const int planes  = (int)(n / ((long long)PH * PW));   // 48

    hipMemsetAsync(d_ws, 0, sizeof(double), stream);       // ws is re-poisoned each launch

    dim3 grid(PW / TILE, PH / TILE, planes);               // 16 x 16 x 48
    nsml_loss_kernel<<<grid, NT, 0, stream>>>(A, B, acc);
    finalize_kernel<<<1, 1, 0, stream>>>(acc, out, 1.0 / (double)n);
}

// Round 2
// 428.258 us; speedup vs baseline: 1.2430x; 1.2430x over previous
//
#include <hip/hip_runtime.h>

#define PW   1024
#define PH   1024
#define SW   8            // strip width per thread
#define ROWS 32           // output rows per thread
#define NSX  (PW / SW)    // 128 strips across
#define NBY  (PH / ROWS)  // 32 bands
#define NT   256

// affine x = (t + 1) * 0.5  (kept as add-then-mul to match reference rounding)
#define AF(v) (((v) + 1.0f) * 0.5f)

// ring-slot helpers (compile-time): at STEP(k), slot k holds row t,
// slot P1(k) holds row t-1, slot P2(k) holds row t-2.
#define P1_0 2
#define P2_0 1
#define P1_1 0
#define P2_1 2
#define P1_2 1
#define P2_2 0

// s-value at column c (c = 0..9 maps to plane col j0-1+c) for tensor X,
// rows: X[p2]=t-2(up), X[p1]=t-1(center row), X[kk]=t(down)
#define SVAL(X, p2, p1, kk, c, outv)                                      \
  {                                                                       \
    float cen_  = X[p1][(c) + 1];                                         \
    float orth_ = fabsf(cen_ - X[p2][(c) + 1])                            \
                + fabsf(cen_ - X[kk][(c) + 1])                            \
                + fabsf(cen_ - X[p1][(c)])                                \
                + fabsf(cen_ - X[p1][(c) + 2]);                           \
    float diag_ = fabsf(cen_ - X[p2][(c)])                                \
                + fabsf(cen_ - X[kk][(c) + 2])                            \
                + fabsf(cen_ - X[p2][(c) + 2])                            \
                + fabsf(cen_ - X[kk][(c)]);                               \
    outv = fmaf(0.707f, diag_, orth_);                                    \
  }

#define STORE12(X, k, a2, b4, c4, d2)                                     \
  X[k][0] = AF(a2.x);  X[k][1] = AF(a2.y);                                \
  X[k][2] = AF(b4.x);  X[k][3] = AF(b4.y);                                \
  X[k][4] = AF(b4.z);  X[k][5] = AF(b4.w);                                \
  X[k][6] = AF(c4.x);  X[k][7] = AF(c4.y);                                \
  X[k][8] = AF(c4.z);  X[k][9] = AF(c4.w);                                \
  X[k][10] = AF(d2.x); X[k][11] = AF(d2.y);

#define STEP(k, p2c, p1c)                                                 \
  {                                                                       \
    const int rr = t < 0 ? 0 : (t >= PH ? PH - 1 : t);                    \
    const float* rpA = pA + (size_t)rr * PW;                              \
    const float* rpB = pB + (size_t)rr * PW;                              \
    float2 a2A = *(const float2*)(rpA + cm2);                             \
    float4 b4A = *(const float4*)(rpA + j0);                              \
    float4 c4A = *(const float4*)(rpA + j0 + 4);                          \
    float2 d2A = *(const float2*)(rpA + cp2);                             \
    float2 a2B = *(const float2*)(rpB + cm2);                             \
    float4 b4B = *(const float4*)(rpB + j0);                              \
    float4 c4B = *(const float4*)(rpB + j0 + 4);                          \
    float2 d2B = *(const float2*)(rpB + cp2);                             \
    if (eL) { a2A.x = b4A.x; a2A.y = b4A.x; a2B.x = b4B.x; a2B.y = b4B.x; } \
    if (eR) { d2A.x = c4A.w; d2A.y = c4A.w; d2B.x = c4B.w; d2B.y = c4B.w; } \
    STORE12(xA, k, a2A, b4A, c4A, d2A)                                    \
    STORE12(xB, k, a2B, b4B, c4B, d2B)                                    \
    const int sr = t - 1;                                                 \
    if (sr >= srlo && sr <= srhi) {                                       \
      float dd[10];                                                       \
      _Pragma("unroll")                                                   \
      for (int c = 0; c < 10; ++c) {                                      \
        float sA_, sB_;                                                   \
        SVAL(xA, p2c, p1c, k, c, sA_)                                     \
        SVAL(xB, p2c, p1c, k, c, sB_)                                     \
        dd[c] = fmaf(sA_, sA_, -(sB_ * sB_));                             \
      }                                                                   \
      dd[0] *= mL;                                                        \
      dd[9] *= mR;                                                        \
      _Pragma("unroll")                                                   \
      for (int j = 0; j < 8; ++j)                                         \
        h[k][j] = fmaf(2.0f, dd[j + 1], dd[j] + dd[j + 2]);               \
    } else {                                                              \
      _Pragma("unroll")                                                   \
      for (int j = 0; j < 8; ++j) h[k][j] = 0.0f;                         \
    }                                                                     \
    const int orow = t - 2;                                               \
    if (orow >= y0 && orow <= yhi) {                                      \
      _Pragma("unroll")                                                   \
      for (int j = 0; j < 8; ++j) {                                       \
        float g = fmaf(2.0f, h[p1c][j], h[p2c][j] + h[k][j]) * 0.0625f;   \
        facc = fmaf(g, g, facc);                                          \
      }                                                                   \
    }                                                                     \
    ++t;                                                                  \
  }

extern "C" __global__ void __launch_bounds__(NT, 3)
nsml_stream_kernel(const float* __restrict__ A, const float* __restrict__ B,
                   double* __restrict__ acc) {
    __shared__ float wpart[NT / 64];

    const int tid = threadIdx.x;
    const int gid = blockIdx.x * NT + tid;
    const int sx   = gid % NSX;
    const int band = (gid / NSX) % NBY;
    const int pl   = gid / (NSX * NBY);

    const int j0 = sx * SW;
    const int y0 = band * ROWS;
    const int yhi = y0 + ROWS - 1;
    const int srlo = (y0 - 1 < 0) ? 0 : (y0 - 1);
    const int srhi = (y0 + ROWS > PH - 1) ? (PH - 1) : (y0 + ROWS);

    const size_t pbase = (size_t)pl * (size_t)(PH * PW);
    const float* __restrict__ pA = A + pbase;
    const float* __restrict__ pB = B + pbase;

    const bool eL = (sx == 0);
    const bool eR = (sx == NSX - 1);
    const float mL = eL ? 0.0f : 1.0f;
    const float mR = eR ? 0.0f : 1.0f;
    const int cm2 = eL ? 0 : (j0 - 2);          // left float2 (cols j0-2, j0-1)
    const int cp2 = eR ? (PW - 2) : (j0 + 8);   // right float2 (cols j0+8, j0+9)

    float xA[3][12], xB[3][12];
    float h[3][8];
    float facc = 0.0f;

    int t = y0 - 2;  // rows streamed: y0-2 .. y0+33 (36 steps)
    for (int it = 0; it < 12; ++it) {
        STEP(0, P2_0, P1_0)
        STEP(1, P2_1, P1_1)
        STEP(2, P2_2, P1_2)
    }

    // ---- block reduce -> one double atomic ----
    #pragma unroll
    for (int off = 32; off > 0; off >>= 1) facc += __shfl_down(facc, off, 64);
    if ((tid & 63) == 0) wpart[tid >> 6] = facc;
    __syncthreads();
    if (tid == 0) {
        double s = (double)wpart[0] + (double)wpart[1]
                 + (double)wpart[2] + (double)wpart[3];
        atomicAdd(acc, s);
    }
}

extern "C" __global__ void finalize_kernel(const double* __restrict__ acc,
                                           float* __restrict__ out, double inv_n) {
    out[0] = (float)(acc[0] * inv_n);
}

extern "C" void kernel_launch(void* const* d_in, const int* in_sizes, int n_in,
                              void* d_out, int out_size, void* d_ws, size_t ws_size,
                              hipStream_t stream) {
    const float* A = (const float*)d_in[0];
    const float* B = (const float*)d_in[1];
    float* out  = (float*)d_out;
    double* acc = (double*)d_ws;

    const long long n = (long long)in_sizes[0];
    const int planes  = (int)(n / ((long long)PH * PW));   // 48

    hipMemsetAsync(d_ws, 0, sizeof(double), stream);       // ws is re-poisoned each launch

    const int total_threads = NSX * NBY * planes;          // 196608
    nsml_stream_kernel<<<total_threads / NT, NT, 0, stream>>>(A, B, acc);
    finalize_kernel<<<1, 1, 0, stream>>>(acc, out, 1.0 / (double)n);
}